// Round 15
// baseline (496.702 us; speedup 1.0000x reference)
//
#include <hip/hip_runtime.h>
#include <hip/hip_bf16.h>
#include <hip/hip_fp16.h>
#include <stdint.h>

#define NN 50000
#define NE 800000
#define HD 128
#define EPSN 1e-5f
#define CAP 1152000   // padded CSR capacity: NE + NN*7 rounded up
#define NCLS 49       // destination classes (c>>10), 1024 nodes each
#define NSB 196       // scan blocks (NN/256 rounded up)

typedef __hip_bfloat16 bf16;
typedef __attribute__((ext_vector_type(8))) _Float16 half8;
typedef __attribute__((ext_vector_type(4))) float f32x4;

__device__ __forceinline__ float us2f(unsigned short u) { return __uint_as_float((uint32_t)u << 16); }
__device__ __forceinline__ ushort f2us(float f) {
    bf16 b = __float2bfloat16(f);
    return *reinterpret_cast<ushort*>(&b);
}
__device__ __forceinline__ ushort f2h(float f) {
    __half h = __float2half(f);
    return *reinterpret_cast<ushort*>(&h);
}
__device__ __forceinline__ float h2f(ushort u) {
    __half h = *reinterpret_cast<__half*>(&u);
    return __half2float(h);
}

// unpack 8 fp16 (carried in a float4's bits) to fp32
__device__ __forceinline__ void cvt8(float4 v, float* o) {
    uint32_t a = __float_as_uint(v.x), b = __float_as_uint(v.y);
    uint32_t c = __float_as_uint(v.z), d = __float_as_uint(v.w);
    o[0] = h2f((ushort)(a & 0xffff)); o[1] = h2f((ushort)(a >> 16));
    o[2] = h2f((ushort)(b & 0xffff)); o[3] = h2f((ushort)(b >> 16));
    o[4] = h2f((ushort)(c & 0xffff)); o[5] = h2f((ushort)(c >> 16));
    o[6] = h2f((ushort)(d & 0xffff)); o[7] = h2f((ushort)(d >> 16));
}

// canonical fp32 parameter block offsets
#define O_X    0
#define O_CW   100000
#define O_CB   100256
#define O_LNG  100384
#define O_LNB  100512
#define O_BNG  100640
#define O_BNB  100768
#define O_W1   100896
#define O_B1   117280
#define O_W2   117408
#define O_B2   133792
#define O_W3   133920
#define O_B3   150304
#define O_F1W  150432
#define O_F1B  154528
#define O_F2W  154560
#define O_F2B  154624
#define O_TOT  154626

struct Ptrs { const void* p[17]; };

__device__ const int SEG_OFF[18] = {O_X, O_CW, O_CB, O_LNG, O_LNB, O_BNG, O_BNB,
                                    O_W1, O_B1, O_W2, O_B2, O_W3, O_B3,
                                    O_F1W, O_F1B, O_F2W, O_F2B, O_TOT};

// Edge accessor: isL=1 -> int64 storage (read low words), else int32.
__device__ __forceinline__ int eidx(const int* __restrict__ ei, int isL, int which, int e) {
    size_t base = (size_t)which * NE + e;
    return isL ? ei[2 * base] : ei[base];
}

// ---------------- dtype detection ----------------
__global__ void k_detect(const int* __restrict__ ei, const ushort* __restrict__ cw,
                         int* __restrict__ flags) {
    int t = threadIdx.x;   // 256 threads, 1 block
    int v = ei[2 * t + 1] | ei[1000000 + 2 * t + 1];
    int bad = 0;
    if (t < 128) {
        float val = us2f(cw[2 * t]);           // low half if f32, real weight if bf16
        bad = !(fabsf(val) <= 1.0f);           // NaN/Inf -> bad
    }
    for (int o = 32; o; o >>= 1) { v |= __shfl_xor(v, o); bad |= __shfl_xor(bad, o); }
    __shared__ int sv[4], sb[4];
    if ((t & 63) == 0) { sv[t >> 6] = v; sb[t >> 6] = bad; }
    __syncthreads();
    if (t == 0) {
        flags[0] = ((sv[0] | sv[1] | sv[2] | sv[3]) == 0) ? 1 : 0;
        flags[1] = ((sb[0] | sb[1] | sb[2] | sb[3]) == 0) ? 1 : 0;
    }
}

// ------- canonicalize inputs to fp32; fp16 W^T; zero degR/ccR/stats/t0h-zero-row -------
__global__ void k_conv(Ptrs ptrs, const int* __restrict__ flags, float* __restrict__ cp,
                       _Float16* __restrict__ wt, int* __restrict__ degR,
                       int* __restrict__ ccR, float* __restrict__ stats,
                       ushort* __restrict__ t0h) {
    int i = blockIdx.x * 256 + threadIdx.x;
    int isBf = flags[1];
    if (i < O_TOT) {
        int s = 0;
        while (i >= SEG_OFF[s + 1]) s++;
        int local = i - SEG_OFF[s];
        const void* src = ptrs.p[s];
        cp[i] = isBf ? us2f(((const ushort*)src)[local]) : ((const float*)src)[local];
    }
    if (i < 3 * HD * HD) {
        int mat = i >> 14, idx = i & (HD * HD - 1);
        int k = idx >> 7, n = idx & 127;
        const void* src = ptrs.p[7 + 2 * mat];          // W1, W2, W3 raw inputs
        int local = k * HD + n;
        float v = isBf ? us2f(((const ushort*)src)[local]) : ((const float*)src)[local];
        wt[mat * HD * HD + n * HD + k] = (_Float16)v;
    }
    if (i < 8 * NN) degR[i] = (i < NN) ? 1 : 0;   // replica 0: self-loop
    if (i < 32 * NCLS) ccR[i] = 0;                // per-(replica32, class) edge counts
    if (i < 12288) stats[i] = 0.f;                // 3 layers x 16 replicas x 256 stats
    if (i < HD) t0h[(size_t)NN * HD + i] = 0;     // sentinel zero row
}

// ---------------- graph preprocessing ----------------
// Pass 1: degree count (8 XCD-local replicas) + per-(replica32, class) edge counts
// (LDS-staged: one global atomic per class per block).
__global__ __launch_bounds__(256) void k_count(const int* __restrict__ ei,
                                               const int* __restrict__ flags,
                                               int* __restrict__ degR,
                                               int* __restrict__ ccR) {
    __shared__ int lcc[NCLS];
    int t = threadIdx.x;
    if (t < NCLS) lcc[t] = 0;
    __syncthreads();
    int e = blockIdx.x * 256 + t;
    if (e < NE) {
        int c = eidx(ei, flags[0], 1, e);
        atomicAdd(&degR[(blockIdx.x & 7) * NN + c], 1);
        atomicAdd(&lcc[c >> 10], 1);
    }
    __syncthreads();
    if (t < NCLS && lcc[t] > 0)
        atomicAdd(&ccR[(blockIdx.x & 31) * NCLS + t], lcc[t]);
}

// Scan 1: per-node degree sum -> degO/dinv; per-block exclusive scan of padded
// bucket sizes (nodePref) + block totals (blockSum).
__global__ __launch_bounds__(256) void k_scan1(const int* __restrict__ degR,
                                               int* __restrict__ degO,
                                               float* __restrict__ dinv,
                                               int* __restrict__ nodePref,
                                               int* __restrict__ blockSum) {
    __shared__ int lp[256];
    int i = blockIdx.x * 256 + threadIdx.x;
    int cpad = 0;
    if (i < NN) {
        int d = 0;
#pragma unroll
        for (int r = 0; r < 8; r++) d += degR[r * NN + i];
        degO[i] = d;
        dinv[i] = rsqrtf((float)d);
        cpad = (d - 1 + 7) & ~7;
    }
    lp[threadIdx.x] = cpad;
    __syncthreads();
    if (threadIdx.x == 0) {
        int run = 0;
        for (int t = 0; t < 256; t++) { int v = lp[t]; lp[t] = run; run += v; }
        blockSum[blockIdx.x] = run;
    }
    __syncthreads();
    if (i < NN) nodePref[i] = lp[threadIdx.x];
}

// Scan 2 (1 block): exclusive prefix of blockSum (srw node-ordered bases);
// class bases + per-(replica32, class) append cursors for the partition pass.
__global__ __launch_bounds__(256) void k_scan2(int* __restrict__ blockSum,
                                               const int* __restrict__ ccR,
                                               int* __restrict__ cur2,
                                               int* __restrict__ classBase) {
    __shared__ int sB[NSB], sC[32 * NCLS], tot[NCLS], cb[NCLS + 1];
    int t = threadIdx.x;
    if (t < NSB) sB[t] = blockSum[t];
    for (int j = t; j < 32 * NCLS; j += 256) sC[j] = ccR[j];
    __syncthreads();
    if (t < NCLS) {                     // per-class total over 32 replicas
        int s = 0;
        for (int r = 0; r < 32; r++) s += sC[r * NCLS + t];
        tot[t] = s;
    }
    if (t == 64) {                      // serial scan of block sums (196)
        int run = 0;
        for (int b = 0; b < NSB; b++) { int v = sB[b]; sB[b] = run; run += v; }
    }
    __syncthreads();
    if (t == 0) {                       // prefix class totals (49)
        int run = 0;
        for (int c = 0; c < NCLS; c++) { cb[c] = run; run += tot[c]; }
        cb[NCLS] = run;
    }
    __syncthreads();
    if (t < NCLS) {                     // per-replica cursors within class region
        int base = cb[t];
        for (int r = 0; r < 32; r++) { int v = sC[r * NCLS + t]; sC[r * NCLS + t] = base; base += v; }
        classBase[t] = cb[t];
        if (t == 0) classBase[NCLS] = cb[NCLS];
    }
    __syncthreads();
    if (t < NSB) blockSum[t] = sB[t];
    for (int j = t; j < 32 * NCLS; j += 256) cur2[j] = sC[j];
}

// Pass 2: partition edges into class-segmented scratch (appends per
// (replica32, class) cursor -> sequential, write-combined).
__global__ __launch_bounds__(256) void k_part(const int* __restrict__ ei,
                                              const int* __restrict__ flags,
                                              int* __restrict__ cur2,
                                              int2* __restrict__ part) {
    int e = blockIdx.x * 256 + threadIdx.x;
    if (e >= NE) return;
    int isL = flags[0];
    int r = eidx(ei, isL, 0, e);
    int c = eidx(ei, isL, 1, e);
    int p = atomicAdd(&cur2[(blockIdx.x & 31) * NCLS + (c >> 10)], 1);
    part[p] = make_int2(r << 4, c);
}

// Pass 3: fine scatter, ONE BLOCK PER CLASS -> the class's srw window
// (~80 KB, node-ordered so contiguous) stays in one XCD's L2; lines evict once.
__global__ __launch_bounds__(1024) void k_scatter(const int2* __restrict__ part,
                                                  const int* __restrict__ classBase,
                                                  int* __restrict__ curA,
                                                  int* __restrict__ srw) {
    int cls = blockIdx.x;
    int lo = classBase[cls], hi = classBase[cls + 1];
    for (int idx = lo + threadIdx.x; idx < hi; idx += 1024) {
        int2 e = part[idx];
        int p = atomicAdd(&curA[e.y], 1);
        srw[p] = e.x;
    }
}

// ------- embed (relu(x@coordW+b) -> LN -> fp16 h) + finalize CSR alloc -------
// startA[i] = blockBase + nodePref (node-ordered); curA init; zero-row sentinels.

__global__ void k_embed(const float* __restrict__ cp, ushort* __restrict__ h,
                        const int* __restrict__ degO, const int* __restrict__ nodePref,
                        const int* __restrict__ blockSum, int* __restrict__ startA,
                        int* __restrict__ curA, int* __restrict__ srw) {
    int gi = blockIdx.x * 256 + threadIdx.x;
    if (gi < NN) {
        int s = blockSum[gi >> 8] + nodePref[gi];
        startA[gi] = s;
        curA[gi] = s;
        int cnt = degO[gi] - 1;
        int cpad = (cnt + 7) & ~7;
        for (int p = s + cnt; p < s + cpad; p++) srw[p] = NN << 4;  // zero-row sentinels
    }
    int node = gi >> 6;
    int lane = threadIdx.x & 63;
    if (node >= NN) return;
    const float* X = cp + O_X;
    const float* CW = cp + O_CW;
    const float* CB = cp + O_CB;
    const float* LG = cp + O_LNG;
    const float* LB = cp + O_LNB;
    float x0 = X[node * 2], x1 = X[node * 2 + 1];
    int f0 = lane, f1 = lane + 64;
    float v0 = fmaxf(0.f, x0 * CW[f0] + x1 * CW[HD + f0] + CB[f0]);
    float v1 = fmaxf(0.f, x0 * CW[f1] + x1 * CW[HD + f1] + CB[f1]);
    float s = v0 + v1, q = v0 * v0 + v1 * v1;
    for (int o = 32; o; o >>= 1) { s += __shfl_xor(s, o); q += __shfl_xor(q, o); }
    float m = s * (1.f / HD);
    float var = q * (1.f / HD) - m * m;
    float r = rsqrtf(var + EPSN);
    h[(size_t)node * HD + f0] = f2h((v0 - m) * r * LG[f0] + LB[f0]);
    h[(size_t)node * HD + f1] = f2h((v1 - m) * r * LG[f1] + LB[f1]);
}

// ------- shared MFMA tile: 64 nodes x 128 feats, 4 waves, 16x16x32 f16 -------
// hl: [64][128] fp16, 16B chunks XOR-swizzled; wt: Wt[n][k] fp16.
// Output PRE-SCALED by dinv[node] -> aggregation is an unweighted gather-sum.

__device__ __forceinline__ void mfma_tile(const _Float16* hl, const _Float16* __restrict__ wt,
                                          const float* __restrict__ dinv,
                                          ushort* __restrict__ t0h, int nodeBase, int t) {
    int w = t >> 6, l = t & 63;
    int m16 = l & 15;              // A-row / D-col index within tile
    int kg = l >> 4;               // k-group 0..3
    int node0 = w * 16;            // wave's M-tile inside the 64-node block
    half8 a[4];
#pragma unroll
    for (int kc = 0; kc < 4; kc++) {
        int nd = node0 + m16;
        int c16 = kc * 4 + kg;                       // 16B chunk = k0/8
        int chunk = nd * 16 + (c16 ^ (nd & 7));
        a[kc] = *(const half8*)(hl + chunk * 8);
    }
    f32x4 acc[8];
#pragma unroll
    for (int nt = 0; nt < 8; nt++) acc[nt] = (f32x4){0.f, 0.f, 0.f, 0.f};
#pragma unroll
    for (int nt = 0; nt < 8; nt++) {
        const half8* bp = (const half8*)(wt + (size_t)(nt * 16 + m16) * HD);
#pragma unroll
        for (int kc = 0; kc < 4; kc++) {
            acc[nt] = __builtin_amdgcn_mfma_f32_16x16x32_f16(a[kc], bp[kc * 4 + kg],
                                                             acc[nt], 0, 0, 0);
        }
    }
    // D layout: col = lane&15 (feature), row = (lane>>4)*4 + reg (node)
    int ndb = nodeBase + node0 + kg * 4;
#pragma unroll
    for (int rr = 0; rr < 4; rr++) {
        int nd = ndb + rr;
        if (nd < NN) {
            float dv = dinv[nd];
#pragma unroll
            for (int nt = 0; nt < 8; nt++) {
                t0h[(size_t)nd * HD + nt * 16 + m16] = f2h(acc[nt][rr] * dv);
            }
        }
    }
}

// ------- GEMM (layer 0): t0h = fp16(dinv * (h @ W)) via MFMA; h already fp16 -------

__global__ __launch_bounds__(256) void k_gemm(const ushort* __restrict__ h,
                                              const _Float16* __restrict__ wt,
                                              const float* __restrict__ dinv,
                                              ushort* __restrict__ t0h) {
    __shared__ _Float16 hl[64 * HD];    // 16 KB swizzled fp16 tile
    int t = threadIdx.x;
    int nodeBase = blockIdx.x * 64;
    const uint4* h4 = (const uint4*)h;   // 16B = 8 fp16
#pragma unroll
    for (int r = 0; r < 4; r++) {
        int cid = r * 256 + t;          // 16B-chunk id 0..1023
        int node = cid >> 4;
        int c16 = cid & 15;
        int n = nodeBase + node;
        uint4 v = make_uint4(0u, 0u, 0u, 0u);
        if (n < NN) v = h4[(size_t)n * 16 + c16];
        int chunk = node * 16 + (c16 ^ (node & 7));
        *(uint4*)(hl + chunk * 8) = v;
    }
    __syncthreads();
    mfma_tile(hl, wt, dinv, t0h, nodeBase, t);
}

// ------- fused BN+residual+InstanceNorm + MFMA GEMM (layers 1,2) -------
// stats region: 16 replicas x 256 (sum[128], sumsq[128]) per layer. h fp16, agg fp32.

__global__ __launch_bounds__(256) void k_gemm_fused(const float* __restrict__ agg,
                                                    const float* __restrict__ stats,
                                                    const float* __restrict__ bias,
                                                    const float* __restrict__ bng,
                                                    const float* __restrict__ bnb,
                                                    ushort* __restrict__ h,
                                                    const _Float16* __restrict__ wt,
                                                    const float* __restrict__ dinv,
                                                    ushort* __restrict__ t0h) {
    __shared__ _Float16 hl[64 * HD];    // 16 KB swizzled fp16 tile
    __shared__ float scL[HD], shL[HD], bL[HD];
    int t = threadIdx.x;
    if (t < 128) {
        const float invN = 1.f / NN;
        float sv = 0.f, qv = 0.f;
#pragma unroll
        for (int r = 0; r < 16; r++) { sv += stats[r * 256 + t]; qv += stats[r * 256 + 128 + t]; }
        float m = sv * invN;
        float v = qv * invN - m * m;
        float sc = bng[t] * rsqrtf(v + EPSN);
        scL[t] = sc;
        shL[t] = bnb[t] - m * sc;
        bL[t] = bias[t];
    }
    __syncthreads();
    int nodeBase = blockIdx.x * 64;
    const float4* a4 = (const float4*)agg;
    const ushort4* h4r = (const ushort4*)h;
    ushort4* h4w = (ushort4*)h;
#pragma unroll
    for (int r = 0; r < 8; r++) {
        int idx = r * 256 + t;          // 0..2047: 64 nodes x 32 slots
        int node = idx >> 5;
        int c4 = idx & 31;
        int n = nodeBase + node;
        float4 u = make_float4(0.f, 0.f, 0.f, 0.f);
        if (n < NN) {
            float4 av = a4[(size_t)n * 32 + c4];
            ushort4 hv = h4r[(size_t)n * 32 + c4];
            int f = c4 * 4;
            float y0 = fmaxf(0.f, av.x + bL[f]);
            float y1 = fmaxf(0.f, av.y + bL[f + 1]);
            float y2 = fmaxf(0.f, av.z + bL[f + 2]);
            float y3 = fmaxf(0.f, av.w + bL[f + 3]);
            u.x = y0 * scL[f]     + shL[f]     + h2f(hv.x);
            u.y = y1 * scL[f + 1] + shL[f + 1] + h2f(hv.y);
            u.z = y2 * scL[f + 2] + shL[f + 2] + h2f(hv.z);
            u.w = y3 * scL[f + 3] + shL[f + 3] + h2f(hv.w);
        }
        float s = u.x + u.y + u.z + u.w;
        float q = u.x * u.x + u.y * u.y + u.z * u.z + u.w * u.w;
        for (int o = 16; o; o >>= 1) { s += __shfl_xor(s, o); q += __shfl_xor(q, o); }
        float m = s * (1.f / HD);
        float var = q * (1.f / HD) - m * m;
        float rr = rsqrtf(var + EPSN);
        u.x = (u.x - m) * rr; u.y = (u.y - m) * rr;
        u.z = (u.z - m) * rr; u.w = (u.w - m) * rr;
        ushort4 pk;
        pk.x = f2h(u.x); pk.y = f2h(u.y); pk.z = f2h(u.z); pk.w = f2h(u.w);
        if (n < NN) h4w[(size_t)n * 32 + c4] = pk;
        // fp16 into swizzled LDS: this thread owns the (c4&1) 8B half of chunk c4>>1
        int chunk = node * 16 + ((c4 >> 1) ^ (node & 7));
        *(ushort4*)((char*)hl + chunk * 16 + (c4 & 1) * 8) = pk;
    }
    __syncthreads();
    mfma_tile(hl, wt, dinv, t0h, nodeBase, t);
}

// ------- aggregate: agg[i] = di*(sum_in t0h'[r] + t0h'[i]); fused BN stats -------
// t0h' pre-scaled by dinv -> unweighted gather-sum; srw = 4B row indices
// (sentinels = zero row NN). One wave per node, 4 edge-groups x 16 lanes,
// 16B/lane row gathers; coalesced 32-edge index loads; gathers back-to-back.
// BN stats -> one of 16 replicas. agg fp32 (pre-BN; fp16 fails accuracy).

__global__ __launch_bounds__(256) void k_agg(const ushort* __restrict__ t0h,
                                             const int* __restrict__ srw,
                                             const int* __restrict__ startA,
                                             const int* __restrict__ deg,
                                             const float* __restrict__ dinv,
                                             const float* __restrict__ bias,
                                             float* __restrict__ agg,
                                             float* __restrict__ stats) {
    int t = threadIdx.x;
    int w = t >> 6;            // wave in block (0..3)
    int l = t & 63;            // lane in wave
    int g = l >> 4;            // edge group 0..3
    int k = l & 15;            // float4 slot in row: features 8k..8k+7
    int l32 = l & 31;          // edge slot within a 32-edge chunk
    const float4* t04 = (const float4*)t0h;
    float4* agg4 = (float4*)agg;
    float bs[8];
    {
        const float4* b4 = (const float4*)bias;
        float4 u0 = b4[2 * k], u1 = b4[2 * k + 1];
        bs[0] = u0.x; bs[1] = u0.y; bs[2] = u0.z; bs[3] = u0.w;
        bs[4] = u1.x; bs[5] = u1.y; bs[6] = u1.z; bs[7] = u1.w;
    }
    float rs1[8], rs2[8];
#pragma unroll
    for (int m = 0; m < 8; m++) { rs1[m] = 0.f; rs2[m] = 0.f; }
    int stride = gridDim.x * 4;
    int i = blockIdx.x * 4 + w;
    int s = 0, nb = 0;
    float di = 0.f;
    if (i < NN) {               // meta for first node
        s = startA[i];
        nb = (deg[i] - 1 + 7) & ~7;
        di = dinv[i];
    }
    while (i < NN) {
        // issue: self-row gather + chunk-0 index load (parallel)
        float4 sv = t04[(size_t)i * 16 + k];
        int ex = 0;
        if (l32 < nb) ex = srw[s + l32];     // 32 edges' indices in one coalesced load
        int nb4 = nb >> 2;                   // 4-edge sub-batches (even; pad is mult-8)
        float4 gg[8];
#define GATH(b) { int rv = __shfl(ex, 4 * (b) + g); \
                  gg[b] = t04[(size_t)(uint32_t)rv + k]; }
        if (nb4 > 0) { GATH(0) GATH(1) }
        if (nb4 > 2) { GATH(2) GATH(3) }
        if (nb4 > 4) { GATH(4) GATH(5) }
        if (nb4 > 6) { GATH(6) GATH(7) }
#undef GATH
        // next-node meta: issued after the gathers -> stays in flight while we wait
        int inext = i + stride;
        int sN = 0, nbN = 0;
        float diN = 0.f;
        if (inext < NN) {
            sN = startA[inext];
            nbN = (deg[inext] - 1 + 7) & ~7;
            diN = dinv[inext];
        }
        // accumulate: self term first (group 0 only), then unweighted edge sums
        float acc[8], c8[8];
        cvt8(sv, c8);
        float ws = (g == 0) ? 1.f : 0.f;
#pragma unroll
        for (int m = 0; m < 8; m++) acc[m] = ws * c8[m];
#define ACCB(b) { float d8[8]; cvt8(gg[b], d8); \
                  _Pragma("unroll") \
                  for (int m = 0; m < 8; m++) acc[m] += d8[m]; }
        if (nb4 > 0) { ACCB(0) ACCB(1) }
        if (nb4 > 2) { ACCB(2) ACCB(3) }
        if (nb4 > 4) { ACCB(4) ACCB(5) }
        if (nb4 > 6) { ACCB(6) ACCB(7) }
#undef ACCB
        // rare tail: nodes with more than 32 in-edges, 32-edge chunks, 8-edge steps
        for (int j = 32; j < nb; j += 32) {
            int ex2 = 0;
            if (j + l32 < nb) ex2 = srw[s + j + l32];
            int rem4 = (nb - j) >> 2;
            if (rem4 > 8) rem4 = 8;
            for (int b = 0; b < rem4; b += 2) {
                int r0 = __shfl(ex2, 4 * b + g);
                int r1 = __shfl(ex2, 4 * b + 4 + g);
                float4 g0 = t04[(size_t)(uint32_t)r0 + k];
                float4 g1 = t04[(size_t)(uint32_t)r1 + k];
                float d0[8], d1[8];
                cvt8(g0, d0); cvt8(g1, d1);
#pragma unroll
                for (int m = 0; m < 8; m++) acc[m] += d0[m] + d1[m];
            }
        }
        // combine the 4 edge-groups (and self term) across the wave; apply di factor
#pragma unroll
        for (int m = 0; m < 8; m++) {
            acc[m] += __shfl_xor(acc[m], 16);
            acc[m] += __shfl_xor(acc[m], 32);
            acc[m] *= di;
        }
        if (g == 0) {
            agg4[(size_t)i * 32 + 2 * k]     = make_float4(acc[0], acc[1], acc[2], acc[3]);
            agg4[(size_t)i * 32 + 2 * k + 1] = make_float4(acc[4], acc[5], acc[6], acc[7]);
        }
#pragma unroll
        for (int m = 0; m < 8; m++) {
            float y = fmaxf(0.f, acc[m] + bs[m]);
            rs1[m] += y;
            rs2[m] += y * y;
        }
        i = inext; s = sN; nb = nbN; di = diN;
    }
    // block-level BN-stat reduction -> LDS -> one atomic per feature per block,
    // into replica (blockIdx & 15).
    __shared__ float s1[4][HD], s2[4][HD];
    if (l < 16) {
#pragma unroll
        for (int m = 0; m < 8; m++) {
            s1[w][k * 8 + m] = rs1[m];
            s2[w][k * 8 + m] = rs2[m];
        }
    }
    __syncthreads();
    float* st = stats + (blockIdx.x & 15) * 256;
    if (t < 128) {
        atomicAdd(&st[t], s1[0][t] + s1[1][t] + s1[2][t] + s1[3][t]);
    } else {
        int f = t - 128;
        atomicAdd(&st[128 + f], s2[0][f] + s2[1][f] + s2[2][f] + s2[3][f]);
    }
}

// ------- fused tail: BN apply + residual + InstanceNorm + FC head (layer 3) -------

__global__ __launch_bounds__(256) void k_tail(const float* __restrict__ agg,
                                              const float* __restrict__ stats,
                                              const ushort* __restrict__ h,
                                              const float* __restrict__ cp,
                                              const int* __restrict__ flags,
                                              void* __restrict__ outv) {
    __shared__ float W1l[HD * 32];   // 16 KB, flat [k][f]
    __shared__ float ub[4][HD];
    __shared__ float scT[HD], shT[HD], bT[HD];
    __shared__ float B1s[32], W2s[64], B2s[2];
    int t = threadIdx.x;
    const float4* f1w4 = (const float4*)(cp + O_F1W);
    float4* w14 = (float4*)W1l;
#pragma unroll
    for (int r = 0; r < 4; r++) w14[r * 256 + t] = f1w4[r * 256 + t];
    if (t < 32) B1s[t] = cp[O_F1B + t];
    if (t < 64) W2s[t] = cp[O_F2W + t];
    if (t < 2) B2s[t] = cp[O_F2B + t];
    if (t < 128) {
        const float invN = 1.f / NN;
        float sv = 0.f, qv = 0.f;
#pragma unroll
        for (int r = 0; r < 16; r++) { sv += stats[r * 256 + t]; qv += stats[r * 256 + 128 + t]; }
        float m = sv * invN;
        float v = qv * invN - m * m;
        float sc = cp[O_BNG + t] * rsqrtf(v + EPSN);
        scT[t] = sc;
        shT[t] = cp[O_BNB + t] - m * sc;
        bT[t] = cp[O_B3 + t];
    }
    __syncthreads();
    int isBf = flags[1];
    int w = t >> 6, l = t & 63;
    int f = l & 31, half = l >> 5;
    for (int base = blockIdx.x * 4; base < NN; base += gridDim.x * 4) {
        int node = base + w;
        if (node >= NN) continue;
        size_t o = (size_t)node * HD;
        float a0 = agg[o + l], a1 = agg[o + l + 64];
        float h0 = h2f(h[o + l]), h1 = h2f(h[o + l + 64]);
        float y0 = fmaxf(0.f, a0 + bT[l]);
        float y1 = fmaxf(0.f, a1 + bT[l + 64]);
        float u0 = y0 * scT[l]      + shT[l]      + h0;
        float u1 = y1 * scT[l + 64] + shT[l + 64] + h1;
        float s = u0 + u1, q = u0 * u0 + u1 * u1;
        for (int oo = 32; oo; oo >>= 1) { s += __shfl_xor(s, oo); q += __shfl_xor(q, oo); }
        float m = s * (1.f / HD);
        float var = q * (1.f / HD) - m * m;
        float r = rsqrtf(var + EPSN);
        u0 = (u0 - m) * r; u1 = (u1 - m) * r;
        ub[w][l] = u0; ub[w][l + 64] = u1;
        // FC1: lane computes partial over its k-half for output feature f
        float acc = (half == 0) ? B1s[f] : 0.f;
        const float* up = ub[w] + half * 64;
        const float* wp = W1l + half * 64 * 32 + f;
#pragma unroll 16
        for (int kk = 0; kk < 64; kk++) acc += up[kk] * wp[kk * 32];
        acc += __shfl_xor(acc, 32);
        float av = fmaxf(0.f, acc);
        float p0 = av * W2s[f * 2], p1 = av * W2s[f * 2 + 1];
        for (int oo = 16; oo; oo >>= 1) { p0 += __shfl_xor(p0, oo); p1 += __shfl_xor(p1, oo); }
        if (l == 0) {
            p0 = tanhf(p0 + B2s[0]); p1 = tanhf(p1 + B2s[1]);
            if (isBf) {
                ((uint32_t*)outv)[node] = (uint32_t)f2us(p0) | ((uint32_t)f2us(p1) << 16);
            } else {
                float2 ov; ov.x = p0; ov.y = p1;
                ((float2*)outv)[node] = ov;
            }
        }
    }
}

// ---------------- launch ----------------

extern "C" void kernel_launch(void* const* d_in, const int* in_sizes, int n_in,
                              void* d_out, int out_size, void* d_ws, size_t ws_size,
                              hipStream_t stream) {
    const int* ei = (const int*)d_in[1];

    Ptrs ptrs;
    ptrs.p[0] = d_in[0];                                  // x
    for (int s = 1; s < 17; s++) ptrs.p[s] = d_in[s + 1]; // coord_W .. fc2_b

    char* wsp = (char*)d_ws;
    size_t off = 0;
    auto alloc = [&](size_t bytes) {
        void* p = wsp + off;
        off += (bytes + 255) & ~(size_t)255;
        return p;
    };
    float* cp     = (float*)alloc((size_t)O_TOT * 4);       // 0.62 MB canonical fp32 params
    ushort* h     = (ushort*)alloc((size_t)NN * HD * 2);    // 12.8 MB fp16 residual stream
    ushort* t0h   = (ushort*)alloc((size_t)(NN + 1) * HD * 2); // 12.8 MB fp16 (+zero row NN)
    float* agg    = (float*)alloc((size_t)NN * HD * 4);     // 25.6 MB fp32 (pre-BN)
    int* degR     = (int*)alloc((size_t)8 * NN * 4);        // 1.6 MB XCD-local replicas
    int* degO     = (int*)alloc((size_t)NN * 4);            // summed degree
    float* dinv   = (float*)alloc((size_t)NN * 4);
    int* srw      = (int*)alloc((size_t)CAP * 4);           // 4.6 MB padded CSR (rows only)
    int2* part    = (int2*)alloc((size_t)NE * 8);           // 6.4 MB class-partitioned edges
    int* startA   = (int*)alloc((size_t)NN * 4);
    int* curA     = (int*)alloc((size_t)NN * 4);
    int* nodePref = (int*)alloc((size_t)NN * 4);
    int* blockSum = (int*)alloc((size_t)NSB * 4);
    int* classBase= (int*)alloc((size_t)(NCLS + 1) * 4);
    int* ccR      = (int*)alloc((size_t)32 * NCLS * 4);
    int* cur2     = (int*)alloc((size_t)32 * NCLS * 4);
    float* stats  = (float*)alloc(3 * 4096 * 4);            // 3 layers x 16 replicas x 256
    int* flags    = (int*)alloc(256);
    _Float16* wt  = (_Float16*)alloc((size_t)3 * HD * HD * 2);  // 96 KB fp16 W^T

    const int BN_EDGE = (NE + 255) / 256;    // 3125
    const int BN_CONV = (8 * NN + 255) / 256; // 1563 (covers O_TOT, 3*HD*HD, 8*NN)
    const int BN_GEMM = (NN + 63) / 64;      // 782

    const float* B[3] = {cp + O_B1, cp + O_B2, cp + O_B3};

    k_detect<<<1, 256, 0, stream>>>(ei, (const ushort*)d_in[2], flags);
    k_conv<<<BN_CONV, 256, 0, stream>>>(ptrs, flags, cp, wt, degR, ccR, stats, t0h);
    k_count<<<BN_EDGE, 256, 0, stream>>>(ei, flags, degR, ccR);
    k_scan1<<<NSB, 256, 0, stream>>>(degR, degO, dinv, nodePref, blockSum);
    k_scan2<<<1, 256, 0, stream>>>(blockSum, ccR, cur2, classBase);
    k_embed<<<NN / 4, 256, 0, stream>>>(cp, h, degO, nodePref, blockSum, startA, curA, srw);
    k_part<<<BN_EDGE, 256, 0, stream>>>(ei, flags, cur2, part);
    k_scatter<<<NCLS, 1024, 0, stream>>>(part, classBase, curA, srw);

    k_gemm<<<BN_GEMM, 256, 0, stream>>>(h, wt, dinv, t0h);
    k_agg<<<2048, 256, 0, stream>>>(t0h, srw, startA, degO, dinv, B[0], agg, stats);
    for (int l = 1; l < 3; l++) {
        k_gemm_fused<<<BN_GEMM, 256, 0, stream>>>(agg, stats + 4096 * (l - 1),
                                                  B[l - 1], cp + O_BNG, cp + O_BNB,
                                                  h, wt + (size_t)l * HD * HD, dinv, t0h);
        k_agg<<<2048, 256, 0, stream>>>(t0h, srw, startA, degO, dinv, B[l],
                                        agg, stats + 4096 * l);
    }
    k_tail<<<2048, 256, 0, stream>>>(agg, stats + 8192, h, cp, flags, d_out);
}

// Round 16
// 408.911 us; speedup vs baseline: 1.2147x; 1.2147x over previous
//
#include <hip/hip_runtime.h>
#include <hip/hip_bf16.h>
#include <hip/hip_fp16.h>
#include <stdint.h>

#define NN 50000
#define NE 800000
#define HD 128
#define EPSN 1e-5f
#define CAP 1152000   // padded CSR capacity: NE + NN*7 rounded up
#define NCLS 49       // destination classes (c>>10), 1024 nodes each
#define NSB 196       // scan blocks (NN/256 rounded up)

typedef __hip_bfloat16 bf16;
typedef __attribute__((ext_vector_type(8))) _Float16 half8;
typedef __attribute__((ext_vector_type(4))) float f32x4;

__device__ __forceinline__ float us2f(unsigned short u) { return __uint_as_float((uint32_t)u << 16); }
__device__ __forceinline__ ushort f2us(float f) {
    bf16 b = __float2bfloat16(f);
    return *reinterpret_cast<ushort*>(&b);
}
__device__ __forceinline__ ushort f2h(float f) {
    __half h = __float2half(f);
    return *reinterpret_cast<ushort*>(&h);
}
__device__ __forceinline__ float h2f(ushort u) {
    __half h = *reinterpret_cast<__half*>(&u);
    return __half2float(h);
}

// unpack 8 fp16 (carried in a float4's bits) to fp32
__device__ __forceinline__ void cvt8(float4 v, float* o) {
    uint32_t a = __float_as_uint(v.x), b = __float_as_uint(v.y);
    uint32_t c = __float_as_uint(v.z), d = __float_as_uint(v.w);
    o[0] = h2f((ushort)(a & 0xffff)); o[1] = h2f((ushort)(a >> 16));
    o[2] = h2f((ushort)(b & 0xffff)); o[3] = h2f((ushort)(b >> 16));
    o[4] = h2f((ushort)(c & 0xffff)); o[5] = h2f((ushort)(c >> 16));
    o[6] = h2f((ushort)(d & 0xffff)); o[7] = h2f((ushort)(d >> 16));
}

// canonical fp32 parameter block offsets
#define O_X    0
#define O_CW   100000
#define O_CB   100256
#define O_LNG  100384
#define O_LNB  100512
#define O_BNG  100640
#define O_BNB  100768
#define O_W1   100896
#define O_B1   117280
#define O_W2   117408
#define O_B2   133792
#define O_W3   133920
#define O_B3   150304
#define O_F1W  150432
#define O_F1B  154528
#define O_F2W  154560
#define O_F2B  154624
#define O_TOT  154626

struct Ptrs { const void* p[17]; };

__device__ const int SEG_OFF[18] = {O_X, O_CW, O_CB, O_LNG, O_LNB, O_BNG, O_BNB,
                                    O_W1, O_B1, O_W2, O_B2, O_W3, O_B3,
                                    O_F1W, O_F1B, O_F2W, O_F2B, O_TOT};

// Edge accessor: isL=1 -> int64 storage (read low words), else int32.
__device__ __forceinline__ int eidx(const int* __restrict__ ei, int isL, int which, int e) {
    size_t base = (size_t)which * NE + e;
    return isL ? ei[2 * base] : ei[base];
}

// ---------------- dtype detection ----------------
__global__ void k_detect(const int* __restrict__ ei, const ushort* __restrict__ cw,
                         int* __restrict__ flags) {
    int t = threadIdx.x;   // 256 threads, 1 block
    int v = ei[2 * t + 1] | ei[1000000 + 2 * t + 1];
    int bad = 0;
    if (t < 128) {
        float val = us2f(cw[2 * t]);           // low half if f32, real weight if bf16
        bad = !(fabsf(val) <= 1.0f);           // NaN/Inf -> bad
    }
    for (int o = 32; o; o >>= 1) { v |= __shfl_xor(v, o); bad |= __shfl_xor(bad, o); }
    __shared__ int sv[4], sb[4];
    if ((t & 63) == 0) { sv[t >> 6] = v; sb[t >> 6] = bad; }
    __syncthreads();
    if (t == 0) {
        flags[0] = ((sv[0] | sv[1] | sv[2] | sv[3]) == 0) ? 1 : 0;
        flags[1] = ((sb[0] | sb[1] | sb[2] | sb[3]) == 0) ? 1 : 0;
    }
}

// ------- canonicalize inputs to fp32; fp16 W^T; zero degR/ccR/stats/t0h-zero-row -------
// ccR/cur2: one cursor per 64B line (stride 16 ints) to kill line ping-pong.
__global__ void k_conv(Ptrs ptrs, const int* __restrict__ flags, float* __restrict__ cp,
                       _Float16* __restrict__ wt, int* __restrict__ degR,
                       int* __restrict__ ccR, float* __restrict__ stats,
                       ushort* __restrict__ t0h) {
    int i = blockIdx.x * 256 + threadIdx.x;
    int isBf = flags[1];
    if (i < O_TOT) {
        int s = 0;
        while (i >= SEG_OFF[s + 1]) s++;
        int local = i - SEG_OFF[s];
        const void* src = ptrs.p[s];
        cp[i] = isBf ? us2f(((const ushort*)src)[local]) : ((const float*)src)[local];
    }
    if (i < 3 * HD * HD) {
        int mat = i >> 14, idx = i & (HD * HD - 1);
        int k = idx >> 7, n = idx & 127;
        const void* src = ptrs.p[7 + 2 * mat];          // W1, W2, W3 raw inputs
        int local = k * HD + n;
        float v = isBf ? us2f(((const ushort*)src)[local]) : ((const float*)src)[local];
        wt[mat * HD * HD + n * HD + k] = (_Float16)v;
    }
    if (i < 8 * NN) degR[i] = (i < NN) ? 1 : 0;   // replica 0: self-loop
    if (i < 32 * NCLS * 16) ccR[i] = 0;           // padded per-(replica32, class) counts
    if (i < 12288) stats[i] = 0.f;                // 3 layers x 16 replicas x 256 stats
    if (i < HD) t0h[(size_t)NN * HD + i] = 0;     // sentinel zero row
}

// ---------------- graph preprocessing ----------------
// Pass 1: degree count (8 XCD-local replicas) + per-(replica32, class) edge counts
// (LDS-staged: one global atomic per class per block; padded cursors).
__global__ __launch_bounds__(256) void k_count(const int* __restrict__ ei,
                                               const int* __restrict__ flags,
                                               int* __restrict__ degR,
                                               int* __restrict__ ccR) {
    __shared__ int lcc[NCLS];
    int t = threadIdx.x;
    if (t < NCLS) lcc[t] = 0;
    __syncthreads();
    int e = blockIdx.x * 256 + t;
    if (e < NE) {
        int c = eidx(ei, flags[0], 1, e);
        atomicAdd(&degR[(blockIdx.x & 7) * NN + c], 1);
        atomicAdd(&lcc[c >> 10], 1);
    }
    __syncthreads();
    if (t < NCLS && lcc[t] > 0)
        atomicAdd(&ccR[((blockIdx.x & 31) * NCLS + t) * 16], lcc[t]);
}

// Scan 1: per-node degree sum -> degO/dinv; per-block exclusive scan of padded
// bucket sizes (nodePref) + block totals (blockSum).
__global__ __launch_bounds__(256) void k_scan1(const int* __restrict__ degR,
                                               int* __restrict__ degO,
                                               float* __restrict__ dinv,
                                               int* __restrict__ nodePref,
                                               int* __restrict__ blockSum) {
    __shared__ int lp[256];
    int i = blockIdx.x * 256 + threadIdx.x;
    int cpad = 0;
    if (i < NN) {
        int d = 0;
#pragma unroll
        for (int r = 0; r < 8; r++) d += degR[r * NN + i];
        degO[i] = d;
        dinv[i] = rsqrtf((float)d);
        cpad = (d - 1 + 7) & ~7;
    }
    lp[threadIdx.x] = cpad;
    __syncthreads();
    if (threadIdx.x == 0) {
        int run = 0;
        for (int t = 0; t < 256; t++) { int v = lp[t]; lp[t] = run; run += v; }
        blockSum[blockIdx.x] = run;
    }
    __syncthreads();
    if (i < NN) nodePref[i] = lp[threadIdx.x];
}

// Scan 2 (1 block): exclusive prefix of blockSum (srw node-ordered bases);
// class bases + per-(replica32, class) append cursors (padded) for k_part.
__global__ __launch_bounds__(256) void k_scan2(int* __restrict__ blockSum,
                                               const int* __restrict__ ccR,
                                               int* __restrict__ cur2,
                                               int* __restrict__ classBase) {
    __shared__ int sB[NSB], sC[32 * NCLS], tot[NCLS], cb[NCLS + 1];
    int t = threadIdx.x;
    if (t < NSB) sB[t] = blockSum[t];
    for (int j = t; j < 32 * NCLS; j += 256) sC[j] = ccR[j * 16];
    __syncthreads();
    if (t < NCLS) {                     // per-class total over 32 replicas
        int s = 0;
        for (int r = 0; r < 32; r++) s += sC[r * NCLS + t];
        tot[t] = s;
    }
    if (t == 64) {                      // serial scan of block sums (196)
        int run = 0;
        for (int b = 0; b < NSB; b++) { int v = sB[b]; sB[b] = run; run += v; }
    }
    __syncthreads();
    if (t == 0) {                       // prefix class totals (49)
        int run = 0;
        for (int c = 0; c < NCLS; c++) { cb[c] = run; run += tot[c]; }
        cb[NCLS] = run;
    }
    __syncthreads();
    if (t < NCLS) {                     // per-replica cursors within class region
        int base = cb[t];
        for (int r = 0; r < 32; r++) { int v = sC[r * NCLS + t]; sC[r * NCLS + t] = base; base += v; }
        classBase[t] = cb[t];
        if (t == 0) classBase[NCLS] = cb[NCLS];
    }
    __syncthreads();
    if (t < NSB) blockSum[t] = sB[t];
    for (int j = t; j < 32 * NCLS; j += 256) cur2[j * 16] = sC[j];
}

// Pass 2: partition edges into class-segmented scratch. LDS-aggregated:
// per-block LDS histogram gives local offsets; ONE padded global atomic per
// (block, class) reserves the run -> appends are sequential, write-combined.
__global__ __launch_bounds__(256) void k_part(const int* __restrict__ ei,
                                              const int* __restrict__ flags,
                                              int* __restrict__ cur2,
                                              int2* __restrict__ part) {
    __shared__ int lcnt[NCLS], lbase[NCLS];
    int t = threadIdx.x;
    if (t < NCLS) lcnt[t] = 0;
    __syncthreads();
    int e = blockIdx.x * 256 + t;
    int r = 0, c = 0, cls = 0, loc = 0;
    bool valid = (e < NE);
    if (valid) {
        int isL = flags[0];
        r = eidx(ei, isL, 0, e);
        c = eidx(ei, isL, 1, e);
        cls = c >> 10;
        loc = atomicAdd(&lcnt[cls], 1);     // LDS atomic -> local offset
    }
    __syncthreads();
    if (t < NCLS) {
        int n = lcnt[t];
        if (n > 0) lbase[t] = atomicAdd(&cur2[((blockIdx.x & 31) * NCLS + t) * 16], n);
    }
    __syncthreads();
    if (valid) part[lbase[cls] + loc] = make_int2(r << 4, c);
}

// Pass 3: fine scatter, ONE BLOCK PER CLASS with LDS per-node cursors
// (<=1024 nodes/class): position from fast LDS atomics, writes land in the
// class's contiguous ~80KB node-ordered srw window (single-XCD L2-resident).
__global__ __launch_bounds__(1024) void k_scatter(const int2* __restrict__ part,
                                                  const int* __restrict__ classBase,
                                                  const int* __restrict__ startA,
                                                  int* __restrict__ srw) {
    __shared__ int lcur[1024];
    int cls = blockIdx.x;
    int nodeBase = cls << 10;
    int n = nodeBase + threadIdx.x;
    if (n < NN) lcur[threadIdx.x] = startA[n];
    __syncthreads();
    int lo = classBase[cls], hi = classBase[cls + 1];
    for (int idx = lo + threadIdx.x; idx < hi; idx += 1024) {
        int2 e = part[idx];
        int p = atomicAdd(&lcur[e.y - nodeBase], 1);
        srw[p] = e.x;
    }
}

// ------- embed (relu(x@coordW+b) -> LN -> fp16 h) + finalize CSR alloc -------
// startA[i] = blockBase + nodePref (node-ordered); zero-row sentinels.

__global__ void k_embed(const float* __restrict__ cp, ushort* __restrict__ h,
                        const int* __restrict__ degO, const int* __restrict__ nodePref,
                        const int* __restrict__ blockSum, int* __restrict__ startA,
                        int* __restrict__ srw) {
    int gi = blockIdx.x * 256 + threadIdx.x;
    if (gi < NN) {
        int s = blockSum[gi >> 8] + nodePref[gi];
        startA[gi] = s;
        int cnt = degO[gi] - 1;
        int cpad = (cnt + 7) & ~7;
        for (int p = s + cnt; p < s + cpad; p++) srw[p] = NN << 4;  // zero-row sentinels
    }
    int node = gi >> 6;
    int lane = threadIdx.x & 63;
    if (node >= NN) return;
    const float* X = cp + O_X;
    const float* CW = cp + O_CW;
    const float* CB = cp + O_CB;
    const float* LG = cp + O_LNG;
    const float* LB = cp + O_LNB;
    float x0 = X[node * 2], x1 = X[node * 2 + 1];
    int f0 = lane, f1 = lane + 64;
    float v0 = fmaxf(0.f, x0 * CW[f0] + x1 * CW[HD + f0] + CB[f0]);
    float v1 = fmaxf(0.f, x0 * CW[f1] + x1 * CW[HD + f1] + CB[f1]);
    float s = v0 + v1, q = v0 * v0 + v1 * v1;
    for (int o = 32; o; o >>= 1) { s += __shfl_xor(s, o); q += __shfl_xor(q, o); }
    float m = s * (1.f / HD);
    float var = q * (1.f / HD) - m * m;
    float r = rsqrtf(var + EPSN);
    h[(size_t)node * HD + f0] = f2h((v0 - m) * r * LG[f0] + LB[f0]);
    h[(size_t)node * HD + f1] = f2h((v1 - m) * r * LG[f1] + LB[f1]);
}

// ------- shared MFMA tile: 64 nodes x 128 feats, 4 waves, 16x16x32 f16 -------
// hl: [64][128] fp16, 16B chunks XOR-swizzled; wt: Wt[n][k] fp16.
// Output PRE-SCALED by dinv[node] -> aggregation is an unweighted gather-sum.

__device__ __forceinline__ void mfma_tile(const _Float16* hl, const _Float16* __restrict__ wt,
                                          const float* __restrict__ dinv,
                                          ushort* __restrict__ t0h, int nodeBase, int t) {
    int w = t >> 6, l = t & 63;
    int m16 = l & 15;              // A-row / D-col index within tile
    int kg = l >> 4;               // k-group 0..3
    int node0 = w * 16;            // wave's M-tile inside the 64-node block
    half8 a[4];
#pragma unroll
    for (int kc = 0; kc < 4; kc++) {
        int nd = node0 + m16;
        int c16 = kc * 4 + kg;                       // 16B chunk = k0/8
        int chunk = nd * 16 + (c16 ^ (nd & 7));
        a[kc] = *(const half8*)(hl + chunk * 8);
    }
    f32x4 acc[8];
#pragma unroll
    for (int nt = 0; nt < 8; nt++) acc[nt] = (f32x4){0.f, 0.f, 0.f, 0.f};
#pragma unroll
    for (int nt = 0; nt < 8; nt++) {
        const half8* bp = (const half8*)(wt + (size_t)(nt * 16 + m16) * HD);
#pragma unroll
        for (int kc = 0; kc < 4; kc++) {
            acc[nt] = __builtin_amdgcn_mfma_f32_16x16x32_f16(a[kc], bp[kc * 4 + kg],
                                                             acc[nt], 0, 0, 0);
        }
    }
    // D layout: col = lane&15 (feature), row = (lane>>4)*4 + reg (node)
    int ndb = nodeBase + node0 + kg * 4;
#pragma unroll
    for (int rr = 0; rr < 4; rr++) {
        int nd = ndb + rr;
        if (nd < NN) {
            float dv = dinv[nd];
#pragma unroll
            for (int nt = 0; nt < 8; nt++) {
                t0h[(size_t)nd * HD + nt * 16 + m16] = f2h(acc[nt][rr] * dv);
            }
        }
    }
}

// ------- GEMM (layer 0): t0h = fp16(dinv * (h @ W)) via MFMA; h already fp16 -------

__global__ __launch_bounds__(256) void k_gemm(const ushort* __restrict__ h,
                                              const _Float16* __restrict__ wt,
                                              const float* __restrict__ dinv,
                                              ushort* __restrict__ t0h) {
    __shared__ _Float16 hl[64 * HD];    // 16 KB swizzled fp16 tile
    int t = threadIdx.x;
    int nodeBase = blockIdx.x * 64;
    const uint4* h4 = (const uint4*)h;   // 16B = 8 fp16
#pragma unroll
    for (int r = 0; r < 4; r++) {
        int cid = r * 256 + t;          // 16B-chunk id 0..1023
        int node = cid >> 4;
        int c16 = cid & 15;
        int n = nodeBase + node;
        uint4 v = make_uint4(0u, 0u, 0u, 0u);
        if (n < NN) v = h4[(size_t)n * 16 + c16];
        int chunk = node * 16 + (c16 ^ (node & 7));
        *(uint4*)(hl + chunk * 8) = v;
    }
    __syncthreads();
    mfma_tile(hl, wt, dinv, t0h, nodeBase, t);
}

// ------- fused BN+residual+InstanceNorm + MFMA GEMM (layers 1,2) -------
// stats region: 16 replicas x 256 (sum[128], sumsq[128]) per layer. h fp16, agg fp32.

__global__ __launch_bounds__(256) void k_gemm_fused(const float* __restrict__ agg,
                                                    const float* __restrict__ stats,
                                                    const float* __restrict__ bias,
                                                    const float* __restrict__ bng,
                                                    const float* __restrict__ bnb,
                                                    ushort* __restrict__ h,
                                                    const _Float16* __restrict__ wt,
                                                    const float* __restrict__ dinv,
                                                    ushort* __restrict__ t0h) {
    __shared__ _Float16 hl[64 * HD];    // 16 KB swizzled fp16 tile
    __shared__ float scL[HD], shL[HD], bL[HD];
    int t = threadIdx.x;
    if (t < 128) {
        const float invN = 1.f / NN;
        float sv = 0.f, qv = 0.f;
#pragma unroll
        for (int r = 0; r < 16; r++) { sv += stats[r * 256 + t]; qv += stats[r * 256 + 128 + t]; }
        float m = sv * invN;
        float v = qv * invN - m * m;
        float sc = bng[t] * rsqrtf(v + EPSN);
        scL[t] = sc;
        shL[t] = bnb[t] - m * sc;
        bL[t] = bias[t];
    }
    __syncthreads();
    int nodeBase = blockIdx.x * 64;
    const float4* a4 = (const float4*)agg;
    const ushort4* h4r = (const ushort4*)h;
    ushort4* h4w = (ushort4*)h;
#pragma unroll
    for (int r = 0; r < 8; r++) {
        int idx = r * 256 + t;          // 0..2047: 64 nodes x 32 slots
        int node = idx >> 5;
        int c4 = idx & 31;
        int n = nodeBase + node;
        float4 u = make_float4(0.f, 0.f, 0.f, 0.f);
        if (n < NN) {
            float4 av = a4[(size_t)n * 32 + c4];
            ushort4 hv = h4r[(size_t)n * 32 + c4];
            int f = c4 * 4;
            float y0 = fmaxf(0.f, av.x + bL[f]);
            float y1 = fmaxf(0.f, av.y + bL[f + 1]);
            float y2 = fmaxf(0.f, av.z + bL[f + 2]);
            float y3 = fmaxf(0.f, av.w + bL[f + 3]);
            u.x = y0 * scL[f]     + shL[f]     + h2f(hv.x);
            u.y = y1 * scL[f + 1] + shL[f + 1] + h2f(hv.y);
            u.z = y2 * scL[f + 2] + shL[f + 2] + h2f(hv.z);
            u.w = y3 * scL[f + 3] + shL[f + 3] + h2f(hv.w);
        }
        float s = u.x + u.y + u.z + u.w;
        float q = u.x * u.x + u.y * u.y + u.z * u.z + u.w * u.w;
        for (int o = 16; o; o >>= 1) { s += __shfl_xor(s, o); q += __shfl_xor(q, o); }
        float m = s * (1.f / HD);
        float var = q * (1.f / HD) - m * m;
        float rr = rsqrtf(var + EPSN);
        u.x = (u.x - m) * rr; u.y = (u.y - m) * rr;
        u.z = (u.z - m) * rr; u.w = (u.w - m) * rr;
        ushort4 pk;
        pk.x = f2h(u.x); pk.y = f2h(u.y); pk.z = f2h(u.z); pk.w = f2h(u.w);
        if (n < NN) h4w[(size_t)n * 32 + c4] = pk;
        // fp16 into swizzled LDS: this thread owns the (c4&1) 8B half of chunk c4>>1
        int chunk = node * 16 + ((c4 >> 1) ^ (node & 7));
        *(ushort4*)((char*)hl + chunk * 16 + (c4 & 1) * 8) = pk;
    }
    __syncthreads();
    mfma_tile(hl, wt, dinv, t0h, nodeBase, t);
}

// ------- aggregate: agg[i] = di*(sum_in t0h'[r] + t0h'[i]); fused BN stats -------
// t0h' pre-scaled by dinv -> unweighted gather-sum; srw = 4B row indices
// (sentinels = zero row NN). One wave per node, 4 edge-groups x 16 lanes,
// 16B/lane row gathers; coalesced 32-edge index loads; gathers back-to-back.
// BN stats -> one of 16 replicas. agg fp32 (pre-BN; fp16 fails accuracy).

__global__ __launch_bounds__(256) void k_agg(const ushort* __restrict__ t0h,
                                             const int* __restrict__ srw,
                                             const int* __restrict__ startA,
                                             const int* __restrict__ deg,
                                             const float* __restrict__ dinv,
                                             const float* __restrict__ bias,
                                             float* __restrict__ agg,
                                             float* __restrict__ stats) {
    int t = threadIdx.x;
    int w = t >> 6;            // wave in block (0..3)
    int l = t & 63;            // lane in wave
    int g = l >> 4;            // edge group 0..3
    int k = l & 15;            // float4 slot in row: features 8k..8k+7
    int l32 = l & 31;          // edge slot within a 32-edge chunk
    const float4* t04 = (const float4*)t0h;
    float4* agg4 = (float4*)agg;
    float bs[8];
    {
        const float4* b4 = (const float4*)bias;
        float4 u0 = b4[2 * k], u1 = b4[2 * k + 1];
        bs[0] = u0.x; bs[1] = u0.y; bs[2] = u0.z; bs[3] = u0.w;
        bs[4] = u1.x; bs[5] = u1.y; bs[6] = u1.z; bs[7] = u1.w;
    }
    float rs1[8], rs2[8];
#pragma unroll
    for (int m = 0; m < 8; m++) { rs1[m] = 0.f; rs2[m] = 0.f; }
    int stride = gridDim.x * 4;
    int i = blockIdx.x * 4 + w;
    int s = 0, nb = 0;
    float di = 0.f;
    if (i < NN) {               // meta for first node
        s = startA[i];
        nb = (deg[i] - 1 + 7) & ~7;
        di = dinv[i];
    }
    while (i < NN) {
        // issue: self-row gather + chunk-0 index load (parallel)
        float4 sv = t04[(size_t)i * 16 + k];
        int ex = 0;
        if (l32 < nb) ex = srw[s + l32];     // 32 edges' indices in one coalesced load
        int nb4 = nb >> 2;                   // 4-edge sub-batches (even; pad is mult-8)
        float4 gg[8];
#define GATH(b) { int rv = __shfl(ex, 4 * (b) + g); \
                  gg[b] = t04[(size_t)(uint32_t)rv + k]; }
        if (nb4 > 0) { GATH(0) GATH(1) }
        if (nb4 > 2) { GATH(2) GATH(3) }
        if (nb4 > 4) { GATH(4) GATH(5) }
        if (nb4 > 6) { GATH(6) GATH(7) }
#undef GATH
        // next-node meta: issued after the gathers -> stays in flight while we wait
        int inext = i + stride;
        int sN = 0, nbN = 0;
        float diN = 0.f;
        if (inext < NN) {
            sN = startA[inext];
            nbN = (deg[inext] - 1 + 7) & ~7;
            diN = dinv[inext];
        }
        // accumulate: self term first (group 0 only), then unweighted edge sums
        float acc[8], c8[8];
        cvt8(sv, c8);
        float ws = (g == 0) ? 1.f : 0.f;
#pragma unroll
        for (int m = 0; m < 8; m++) acc[m] = ws * c8[m];
#define ACCB(b) { float d8[8]; cvt8(gg[b], d8); \
                  _Pragma("unroll") \
                  for (int m = 0; m < 8; m++) acc[m] += d8[m]; }
        if (nb4 > 0) { ACCB(0) ACCB(1) }
        if (nb4 > 2) { ACCB(2) ACCB(3) }
        if (nb4 > 4) { ACCB(4) ACCB(5) }
        if (nb4 > 6) { ACCB(6) ACCB(7) }
#undef ACCB
        // rare tail: nodes with more than 32 in-edges, 32-edge chunks, 8-edge steps
        for (int j = 32; j < nb; j += 32) {
            int ex2 = 0;
            if (j + l32 < nb) ex2 = srw[s + j + l32];
            int rem4 = (nb - j) >> 2;
            if (rem4 > 8) rem4 = 8;
            for (int b = 0; b < rem4; b += 2) {
                int r0 = __shfl(ex2, 4 * b + g);
                int r1 = __shfl(ex2, 4 * b + 4 + g);
                float4 g0 = t04[(size_t)(uint32_t)r0 + k];
                float4 g1 = t04[(size_t)(uint32_t)r1 + k];
                float d0[8], d1[8];
                cvt8(g0, d0); cvt8(g1, d1);
#pragma unroll
                for (int m = 0; m < 8; m++) acc[m] += d0[m] + d1[m];
            }
        }
        // combine the 4 edge-groups (and self term) across the wave; apply di factor
#pragma unroll
        for (int m = 0; m < 8; m++) {
            acc[m] += __shfl_xor(acc[m], 16);
            acc[m] += __shfl_xor(acc[m], 32);
            acc[m] *= di;
        }
        if (g == 0) {
            agg4[(size_t)i * 32 + 2 * k]     = make_float4(acc[0], acc[1], acc[2], acc[3]);
            agg4[(size_t)i * 32 + 2 * k + 1] = make_float4(acc[4], acc[5], acc[6], acc[7]);
        }
#pragma unroll
        for (int m = 0; m < 8; m++) {
            float y = fmaxf(0.f, acc[m] + bs[m]);
            rs1[m] += y;
            rs2[m] += y * y;
        }
        i = inext; s = sN; nb = nbN; di = diN;
    }
    // block-level BN-stat reduction -> LDS -> one atomic per feature per block,
    // into replica (blockIdx & 15).
    __shared__ float s1[4][HD], s2[4][HD];
    if (l < 16) {
#pragma unroll
        for (int m = 0; m < 8; m++) {
            s1[w][k * 8 + m] = rs1[m];
            s2[w][k * 8 + m] = rs2[m];
        }
    }
    __syncthreads();
    float* st = stats + (blockIdx.x & 15) * 256;
    if (t < 128) {
        atomicAdd(&st[t], s1[0][t] + s1[1][t] + s1[2][t] + s1[3][t]);
    } else {
        int f = t - 128;
        atomicAdd(&st[128 + f], s2[0][f] + s2[1][f] + s2[2][f] + s2[3][f]);
    }
}

// ------- fused tail: BN apply + residual + InstanceNorm + FC head (layer 3) -------

__global__ __launch_bounds__(256) void k_tail(const float* __restrict__ agg,
                                              const float* __restrict__ stats,
                                              const ushort* __restrict__ h,
                                              const float* __restrict__ cp,
                                              const int* __restrict__ flags,
                                              void* __restrict__ outv) {
    __shared__ float W1l[HD * 32];   // 16 KB, flat [k][f]
    __shared__ float ub[4][HD];
    __shared__ float scT[HD], shT[HD], bT[HD];
    __shared__ float B1s[32], W2s[64], B2s[2];
    int t = threadIdx.x;
    const float4* f1w4 = (const float4*)(cp + O_F1W);
    float4* w14 = (float4*)W1l;
#pragma unroll
    for (int r = 0; r < 4; r++) w14[r * 256 + t] = f1w4[r * 256 + t];
    if (t < 32) B1s[t] = cp[O_F1B + t];
    if (t < 64) W2s[t] = cp[O_F2W + t];
    if (t < 2) B2s[t] = cp[O_F2B + t];
    if (t < 128) {
        const float invN = 1.f / NN;
        float sv = 0.f, qv = 0.f;
#pragma unroll
        for (int r = 0; r < 16; r++) { sv += stats[r * 256 + t]; qv += stats[r * 256 + 128 + t]; }
        float m = sv * invN;
        float v = qv * invN - m * m;
        float sc = cp[O_BNG + t] * rsqrtf(v + EPSN);
        scT[t] = sc;
        shT[t] = cp[O_BNB + t] - m * sc;
        bT[t] = cp[O_B3 + t];
    }
    __syncthreads();
    int isBf = flags[1];
    int w = t >> 6, l = t & 63;
    int f = l & 31, half = l >> 5;
    for (int base = blockIdx.x * 4; base < NN; base += gridDim.x * 4) {
        int node = base + w;
        if (node >= NN) continue;
        size_t o = (size_t)node * HD;
        float a0 = agg[o + l], a1 = agg[o + l + 64];
        float h0 = h2f(h[o + l]), h1 = h2f(h[o + l + 64]);
        float y0 = fmaxf(0.f, a0 + bT[l]);
        float y1 = fmaxf(0.f, a1 + bT[l + 64]);
        float u0 = y0 * scT[l]      + shT[l]      + h0;
        float u1 = y1 * scT[l + 64] + shT[l + 64] + h1;
        float s = u0 + u1, q = u0 * u0 + u1 * u1;
        for (int oo = 32; oo; oo >>= 1) { s += __shfl_xor(s, oo); q += __shfl_xor(q, oo); }
        float m = s * (1.f / HD);
        float var = q * (1.f / HD) - m * m;
        float r = rsqrtf(var + EPSN);
        u0 = (u0 - m) * r; u1 = (u1 - m) * r;
        ub[w][l] = u0; ub[w][l + 64] = u1;
        // FC1: lane computes partial over its k-half for output feature f
        float acc = (half == 0) ? B1s[f] : 0.f;
        const float* up = ub[w] + half * 64;
        const float* wp = W1l + half * 64 * 32 + f;
#pragma unroll 16
        for (int kk = 0; kk < 64; kk++) acc += up[kk] * wp[kk * 32];
        acc += __shfl_xor(acc, 32);
        float av = fmaxf(0.f, acc);
        float p0 = av * W2s[f * 2], p1 = av * W2s[f * 2 + 1];
        for (int oo = 16; oo; oo >>= 1) { p0 += __shfl_xor(p0, oo); p1 += __shfl_xor(p1, oo); }
        if (l == 0) {
            p0 = tanhf(p0 + B2s[0]); p1 = tanhf(p1 + B2s[1]);
            if (isBf) {
                ((uint32_t*)outv)[node] = (uint32_t)f2us(p0) | ((uint32_t)f2us(p1) << 16);
            } else {
                float2 ov; ov.x = p0; ov.y = p1;
                ((float2*)outv)[node] = ov;
            }
        }
    }
}

// ---------------- launch ----------------

extern "C" void kernel_launch(void* const* d_in, const int* in_sizes, int n_in,
                              void* d_out, int out_size, void* d_ws, size_t ws_size,
                              hipStream_t stream) {
    const int* ei = (const int*)d_in[1];

    Ptrs ptrs;
    ptrs.p[0] = d_in[0];                                  // x
    for (int s = 1; s < 17; s++) ptrs.p[s] = d_in[s + 1]; // coord_W .. fc2_b

    char* wsp = (char*)d_ws;
    size_t off = 0;
    auto alloc = [&](size_t bytes) {
        void* p = wsp + off;
        off += (bytes + 255) & ~(size_t)255;
        return p;
    };
    float* cp     = (float*)alloc((size_t)O_TOT * 4);       // 0.62 MB canonical fp32 params
    ushort* h     = (ushort*)alloc((size_t)NN * HD * 2);    // 12.8 MB fp16 residual stream
    ushort* t0h   = (ushort*)alloc((size_t)(NN + 1) * HD * 2); // 12.8 MB fp16 (+zero row NN)
    float* agg    = (float*)alloc((size_t)NN * HD * 4);     // 25.6 MB fp32 (pre-BN)
    int* degR     = (int*)alloc((size_t)8 * NN * 4);        // 1.6 MB XCD-local replicas
    int* degO     = (int*)alloc((size_t)NN * 4);            // summed degree
    float* dinv   = (float*)alloc((size_t)NN * 4);
    int* srw      = (int*)alloc((size_t)CAP * 4);           // 4.6 MB padded CSR (rows only)
    int2* part    = (int2*)alloc((size_t)NE * 8);           // 6.4 MB class-partitioned edges
    int* startA   = (int*)alloc((size_t)NN * 4);
    int* nodePref = (int*)alloc((size_t)NN * 4);
    int* blockSum = (int*)alloc((size_t)NSB * 4);
    int* classBase= (int*)alloc((size_t)(NCLS + 1) * 4);
    int* ccR      = (int*)alloc((size_t)32 * NCLS * 16 * 4);  // padded: 1 cursor / 64B line
    int* cur2     = (int*)alloc((size_t)32 * NCLS * 16 * 4);  // padded
    float* stats  = (float*)alloc(3 * 4096 * 4);            // 3 layers x 16 replicas x 256
    int* flags    = (int*)alloc(256);
    _Float16* wt  = (_Float16*)alloc((size_t)3 * HD * HD * 2);  // 96 KB fp16 W^T

    const int BN_EDGE = (NE + 255) / 256;    // 3125
    const int BN_CONV = (8 * NN + 255) / 256; // 1563 (covers O_TOT, 3*HD*HD, 8*NN, ccR pad)
    const int BN_GEMM = (NN + 63) / 64;      // 782

    const float* B[3] = {cp + O_B1, cp + O_B2, cp + O_B3};

    k_detect<<<1, 256, 0, stream>>>(ei, (const ushort*)d_in[2], flags);
    k_conv<<<BN_CONV, 256, 0, stream>>>(ptrs, flags, cp, wt, degR, ccR, stats, t0h);
    k_count<<<BN_EDGE, 256, 0, stream>>>(ei, flags, degR, ccR);
    k_scan1<<<NSB, 256, 0, stream>>>(degR, degO, dinv, nodePref, blockSum);
    k_scan2<<<1, 256, 0, stream>>>(blockSum, ccR, cur2, classBase);
    k_embed<<<NN / 4, 256, 0, stream>>>(cp, h, degO, nodePref, blockSum, startA, srw);
    k_part<<<BN_EDGE, 256, 0, stream>>>(ei, flags, cur2, part);
    k_scatter<<<NCLS, 1024, 0, stream>>>(part, classBase, startA, srw);

    k_gemm<<<BN_GEMM, 256, 0, stream>>>(h, wt, dinv, t0h);
    k_agg<<<2048, 256, 0, stream>>>(t0h, srw, startA, degO, dinv, B[0], agg, stats);
    for (int l = 1; l < 3; l++) {
        k_gemm_fused<<<BN_GEMM, 256, 0, stream>>>(agg, stats + 4096 * (l - 1),
                                                  B[l - 1], cp + O_BNG, cp + O_BNB,
                                                  h, wt + (size_t)l * HD * HD, dinv, t0h);
        k_agg<<<2048, 256, 0, stream>>>(t0h, srw, startA, degO, dinv, B[l],
                                        agg, stats + 4096 * l);
    }
    k_tail<<<2048, 256, 0, stream>>>(agg, stats + 8192, h, cp, flags, d_out);
}